// Round 1
// baseline (634.049 us; speedup 1.0000x reference)
//
#include <hip/hip_runtime.h>
#include <math.h>

// Problem constants
#define N_TOK 32768
#define KCB   4096
#define DIM   64

// Output layout (flat float32)
#define OFF_ZQST   0
#define OFF_ZQ     2097152
#define OFF_IDX    4194304
#define OFF_STATS  4227072
#define OFF_NEWEMB 4227074
#define OFF_NEWCS  4489218
#define OFF_NEWEMA 4493314

// Workspace layout (bytes)
#define WS_FN     0          // 32768*64 f32 = 8388608 B
#define WS_ESUM   8388608    // 4096*64 f32  = 1048576 B
#define WS_USAGE  9437184    // 4096 f32     = 16384 B
#define WS_PMAX   9453568    // 4*32768 f64  = 1048576 B
#define WS_PIDX   10502144   // 4*32768 i32  = 524288 B
#define WS_IDX    11026432   // 32768 i32    = 131072 B
#define WS_RIDX   11157504   // 4096 i32     = 16384 B
#define WS_NVAL   11173888   // 1 f32

constexpr int LDA = 68;  // padded LDS stride (keeps 8B/16B alignment, breaks pow2 banks)

__device__ __forceinline__ float wave_sum(float v) {
#pragma unroll
  for (int off = 32; off > 0; off >>= 1) v += __shfl_xor(v, off, 64);
  return v;
}

// ---------------- Threefry-2x32 (20 rounds), bit-exact vs JAX ----------------
__device__ __forceinline__ unsigned rotl32(unsigned x, int d) {
  return (x << d) | (x >> (32 - d));
}
__device__ __forceinline__ void tf2x32(unsigned k0, unsigned k1,
                                       unsigned x0, unsigned x1,
                                       unsigned& o0, unsigned& o1) {
  unsigned ks2 = k0 ^ k1 ^ 0x1BD11BDAu;
  unsigned v0 = x0 + k0, v1 = x1 + k1;
  // rounds 1-4 (rot 13,15,26,6)
  v0 += v1; v1 = rotl32(v1, 13) ^ v0;
  v0 += v1; v1 = rotl32(v1, 15) ^ v0;
  v0 += v1; v1 = rotl32(v1, 26) ^ v0;
  v0 += v1; v1 = rotl32(v1, 6) ^ v0;
  v0 += k1; v1 += ks2 + 1u;
  // rounds 5-8 (rot 17,29,16,24)
  v0 += v1; v1 = rotl32(v1, 17) ^ v0;
  v0 += v1; v1 = rotl32(v1, 29) ^ v0;
  v0 += v1; v1 = rotl32(v1, 16) ^ v0;
  v0 += v1; v1 = rotl32(v1, 24) ^ v0;
  v0 += ks2; v1 += k0 + 2u;
  // rounds 9-12
  v0 += v1; v1 = rotl32(v1, 13) ^ v0;
  v0 += v1; v1 = rotl32(v1, 15) ^ v0;
  v0 += v1; v1 = rotl32(v1, 26) ^ v0;
  v0 += v1; v1 = rotl32(v1, 6) ^ v0;
  v0 += k0; v1 += k1 + 3u;
  // rounds 13-16
  v0 += v1; v1 = rotl32(v1, 17) ^ v0;
  v0 += v1; v1 = rotl32(v1, 29) ^ v0;
  v0 += v1; v1 = rotl32(v1, 16) ^ v0;
  v0 += v1; v1 = rotl32(v1, 24) ^ v0;
  v0 += k1; v1 += ks2 + 4u;
  // rounds 17-20
  v0 += v1; v1 = rotl32(v1, 13) ^ v0;
  v0 += v1; v1 = rotl32(v1, 15) ^ v0;
  v0 += v1; v1 = rotl32(v1, 26) ^ v0;
  v0 += v1; v1 = rotl32(v1, 6) ^ v0;
  v0 += ks2; v1 += k0 + 5u;
  o0 = v0; o1 = v1;
}

// rand_idx = randint(key(1),(4096,),0,32768). span=2^15 -> multiplier=0 ->
// result = lower_bits & 0x7fff with lower_bits = random_bits(k2), (k1,k2)=split(key(1)).
__global__ void k_ridx(int* __restrict__ ridx) {
  int j = blockIdx.x * 256 + threadIdx.x;  // 0..2047
  unsigned a0, b0, a1, b1;
  tf2x32(0u, 1u, 0u, 2u, a0, b0);  // split pair 0
  tf2x32(0u, 1u, 1u, 3u, a1, b1);  // split pair 1
  // k2 = second row of reshape(2,2) = (b0, b1)
  unsigned o0, o1;
  tf2x32(b0, b1, (unsigned)j, (unsigned)(j + 2048), o0, o1);
  ridx[j] = (int)(o0 & 32767u);
  ridx[j + 2048] = (int)(o1 & 32767u);
}

// ---------------- normalize rows of z_e -> fn ----------------
__global__ __launch_bounds__(256) void k_norm(const float* __restrict__ z_e,
                                              float* __restrict__ fn) {
  int t = threadIdx.x;
  int n = blockIdx.x * 4 + (t >> 6);
  int lane = t & 63;
  float x = z_e[n * 64 + lane];
  float ss = wave_sum(x * x);
  fn[n * 64 + lane] = x / fmaxf(sqrtf(ss), 1e-8f);
}

// ---------------- dots + argmax (fp64 accumulate), 4-way K-split ----------------
__global__ __launch_bounds__(256) void k_dots(const float* __restrict__ fn,
                                              const float* __restrict__ emb,
                                              double* __restrict__ pmax,
                                              int* __restrict__ pidx) {
  __shared__ __align__(16) float As[64 * LDA];
  __shared__ __align__(16) float Bs[64 * LDA];
  int t = threadIdx.x;
  int tq = t & 15, tc = t >> 4;
  int q0 = blockIdx.x * 64;
  int split = blockIdx.y;      // 0..3
  int kbase0 = split * 1024;   // 16 tiles of 64 codes

  // stage A (64 queries x 64 dims), coalesced float4
#pragma unroll
  for (int i = 0; i < 4; i++) {
    int flat = t + 256 * i;
    int q = flat >> 4;
    int d4 = (flat & 15) << 2;
    float4 v = *(const float4*)(fn + (q0 + q) * 64 + d4);
    *(float4*)&As[q * LDA + d4] = v;
  }

  double acc[4][4];
#pragma unroll
  for (int a = 0; a < 4; a++)
#pragma unroll
    for (int b = 0; b < 4; b++) acc[a][b] = 0.0;
  double mmax[4];
  int midx[4];
#pragma unroll
  for (int a = 0; a < 4; a++) { mmax[a] = -1e300; midx[a] = 0; }

  for (int kt = 0; kt < 16; kt++) {
    int kb = kbase0 + kt * 64;
    __syncthreads();  // protect Bs from previous iteration's readers (also covers As stage)
#pragma unroll
    for (int i = 0; i < 4; i++) {
      int flat = t + 256 * i;
      int c = flat >> 4;
      int d4 = (flat & 15) << 2;
      float4 v = *(const float4*)(emb + (kb + c) * 64 + d4);
      *(float4*)&Bs[c * LDA + d4] = v;
    }
    __syncthreads();

#pragma unroll 4
    for (int d2 = 0; d2 < 64; d2 += 2) {
      double a0[4], a1[4], b0[4], b1[4];
#pragma unroll
      for (int j = 0; j < 4; j++) {
        float2 av = *(const float2*)&As[(4 * tq + j) * LDA + d2];
        a0[j] = (double)av.x; a1[j] = (double)av.y;
      }
#pragma unroll
      for (int j = 0; j < 4; j++) {
        float2 bv = *(const float2*)&Bs[(4 * tc + j) * LDA + d2];
        b0[j] = (double)bv.x; b1[j] = (double)bv.y;
      }
#pragma unroll
      for (int qi = 0; qi < 4; qi++)
#pragma unroll
        for (int ci = 0; ci < 4; ci++)
          acc[qi][ci] += a0[qi] * b0[ci] + a1[qi] * b1[ci];
    }

    // fold tile results into running argmax (strict > keeps earliest index)
#pragma unroll
    for (int qi = 0; qi < 4; qi++)
#pragma unroll
      for (int ci = 0; ci < 4; ci++) {
        double v = acc[qi][ci];
        int kidx = kb + 4 * tc + ci;
        if (v > mmax[qi]) { mmax[qi] = v; midx[qi] = kidx; }
        acc[qi][ci] = 0.0;
      }
  }

  // cross-thread (tc) reduction in fp64, reuse LDS
  __syncthreads();
  double* rm = (double*)As;  // 64*17 doubles = 8704 B <= 17408 B
  int* ri = (int*)Bs;
#pragma unroll
  for (int qi = 0; qi < 4; qi++) {
    int q = 4 * tq + qi;
    rm[q * 17 + tc] = mmax[qi];
    ri[q * 17 + tc] = midx[qi];
  }
  __syncthreads();
  if (t < 64) {
    double bm = -1e300;
    int bi = 0;
    for (int c = 0; c < 16; c++) {
      double m = rm[t * 17 + c];
      int i2 = ri[t * 17 + c];
      if (m > bm || (m == bm && i2 < bi)) { bm = m; bi = i2; }
    }
    pmax[split * N_TOK + q0 + t] = bm;
    pidx[split * N_TOK + q0 + t] = bi;
  }
}

// ---------------- combine splits + gather z_q / z_q_st / indices ----------------
__global__ __launch_bounds__(256) void k_gather(const double* __restrict__ pmax,
                                                const int* __restrict__ pidx,
                                                const float* __restrict__ z_e,
                                                const float* __restrict__ emb,
                                                float* __restrict__ out,
                                                int* __restrict__ idxw) {
  int t = threadIdx.x;
  int n = blockIdx.x * 4 + (t >> 6);
  int lane = t & 63;
  double bm = -1e300;
  int bi = 0;
#pragma unroll
  for (int s = 0; s < 4; s++) {
    double m = pmax[s * N_TOK + n];
    int i2 = pidx[s * N_TOK + n];
    if (m > bm || (m == bm && i2 < bi)) { bm = m; bi = i2; }
  }
  float v = emb[bi * 64 + lane];
  float ze = z_e[n * 64 + lane];
  out[OFF_ZQST + n * 64 + lane] = ze + (v - ze);  // mimic z_e + (z_q - z_e) exactly
  out[OFF_ZQ + n * 64 + lane] = v;
  if (lane == 0) {
    idxw[n] = bi;
    out[OFF_IDX + n] = (float)bi;
  }
}

// ---------------- scatter: usage bincount + embed_sum ----------------
__global__ __launch_bounds__(256) void k_scatter(const int* __restrict__ idxw,
                                                 const float* __restrict__ fn,
                                                 float* __restrict__ esum,
                                                 float* __restrict__ usage) {
  int t = threadIdx.x;
  int n = blockIdx.x * 4 + (t >> 6);
  int lane = t & 63;
  int bi = idxw[n];
  atomicAdd(&esum[bi * 64 + lane], fn[n * 64 + lane]);
  if (lane == 0) atomicAdd(&usage[bi], 1.0f);
}

// ---------------- stats (perplexity, dead_ratio) + n = sum(new_cs) ----------------
__device__ __forceinline__ float block_reduce256(float v, float* r, int t) {
  r[t] = v;
  __syncthreads();
  for (int s = 128; s > 0; s >>= 1) {
    if (t < s) r[t] += r[t + s];
    __syncthreads();
  }
  float res = r[0];
  __syncthreads();
  return res;
}

__global__ __launch_bounds__(256) void k_stats(const float* __restrict__ usage,
                                               const float* __restrict__ ema_cs,
                                               float* __restrict__ out,
                                               float* __restrict__ nval) {
  __shared__ float r[256];
  int t = threadIdx.x;
  float su = 0.f, sd = 0.f, scs = 0.f;
  for (int i = t; i < KCB; i += 256) {
    float u = usage[i];
    su += u;
    sd += (u == 0.f) ? 1.f : 0.f;
    scs += 0.99f * ema_cs[i] + 0.01f * u;
  }
  float tot_u = block_reduce256(su, r, t);
  float tot_d = block_reduce256(sd, r, t);
  float tot_cs = block_reduce256(scs, r, t);
  float denom = fmaxf(tot_u, 1.0f);
  float ent = 0.f;
  for (int i = t; i < KCB; i += 256) {
    float p = usage[i] / denom;
    if (p > 0.f) ent += p * logf(p);
  }
  float tot_e = block_reduce256(ent, r, t);
  if (t == 0) {
    out[OFF_STATS + 0] = expf(-tot_e);
    out[OFF_STATS + 1] = tot_d * (1.0f / 4096.0f);
    nval[0] = tot_cs;
  }
}

// ---------------- new_cs, new_ema_emb, new_embedding ----------------
__global__ __launch_bounds__(256) void k_final(const float* __restrict__ usage,
                                               const float* __restrict__ ema_cs,
                                               const float* __restrict__ ema_emb,
                                               const float* __restrict__ esum,
                                               const float* __restrict__ fn,
                                               const int* __restrict__ ridx,
                                               const float* __restrict__ nval,
                                               float* __restrict__ out) {
  int t = threadIdx.x;
  int k = blockIdx.x * 4 + (t >> 6);
  int lane = t & 63;
  float u = usage[k];
  float ncs = 0.99f * ema_cs[k] + 0.01f * u;
  if (lane == 0) out[OFF_NEWCS + k] = ncs;
  float nee = 0.99f * ema_emb[k * 64 + lane] + 0.01f * esum[k * 64 + lane];
  out[OFF_NEWEMA + k * 64 + lane] = nee;

  float n = nval[0];
  float smoothed = (ncs + 1e-5f) / (n + 4096.0f * 1e-5f);
  float ne = nee / fmaxf(smoothed, 1e-5f);
  float ss = wave_sum(ne * ne);
  ne = ne / fmaxf(sqrtf(ss), 1e-8f);

  float res;
  if (u <= 0.f) {  // dead code: reinit from fn[rand_idx[k]] (renormalized)
    int rsrc = ridx[k];
    float v = fn[rsrc * 64 + lane];
    float s2 = wave_sum(v * v);
    res = v / fmaxf(sqrtf(s2), 1e-8f);
  } else {
    res = ne;
  }
  out[OFF_NEWEMB + k * 64 + lane] = res;
}

extern "C" void kernel_launch(void* const* d_in, const int* in_sizes, int n_in,
                              void* d_out, int out_size, void* d_ws, size_t ws_size,
                              hipStream_t stream) {
  const float* z_e = (const float*)d_in[0];
  const float* emb = (const float*)d_in[1];
  const float* ema_cs = (const float*)d_in[2];
  const float* ema_emb = (const float*)d_in[3];
  float* out = (float*)d_out;
  char* ws = (char*)d_ws;

  float* fn = (float*)(ws + WS_FN);
  float* esum = (float*)(ws + WS_ESUM);
  float* usage = (float*)(ws + WS_USAGE);
  double* pmax = (double*)(ws + WS_PMAX);
  int* pidx = (int*)(ws + WS_PIDX);
  int* idxw = (int*)(ws + WS_IDX);
  int* ridx = (int*)(ws + WS_RIDX);
  float* nval = (float*)(ws + WS_NVAL);

  // zero esum + usage (contiguous region)
  hipMemsetAsync(ws + WS_ESUM, 0, 1048576 + 16384, stream);

  k_ridx<<<8, 256, 0, stream>>>(ridx);
  k_norm<<<8192, 256, 0, stream>>>(z_e, fn);
  k_dots<<<dim3(512, 4), 256, 0, stream>>>(fn, emb, pmax, pidx);
  k_gather<<<8192, 256, 0, stream>>>(pmax, pidx, z_e, emb, out, idxw);
  k_scatter<<<8192, 256, 0, stream>>>(idxw, fn, esum, usage);
  k_stats<<<1, 256, 0, stream>>>(usage, ema_cs, out, nval);
  k_final<<<1024, 256, 0, stream>>>(usage, ema_cs, ema_emb, esum, fn, ridx, nval, out);
}

// Round 2
// 262.482 us; speedup vs baseline: 2.4156x; 2.4156x over previous
//
#include <hip/hip_runtime.h>
#include <math.h>

// Problem constants
#define N_TOK 32768
#define KCB   4096
#define DIM   64

// Output layout (flat float32)
#define OFF_ZQST   0
#define OFF_ZQ     2097152
#define OFF_IDX    4194304
#define OFF_STATS  4227072
#define OFF_NEWEMB 4227074
#define OFF_NEWCS  4489218
#define OFF_NEWEMA 4493314

// Workspace layout (bytes)
#define WS_FN       0          // 32768*64 f32 = 8388608
#define WS_EHI      8388608    // 4096*64 u16  = 524288
#define WS_ELO      8912896    // 4096*64 u16  = 524288
#define WS_ESUM     9437184    // 4096*64 f32  = 1048576
#define WS_USAGE    10485760   // 4096 f32     = 16384
#define WS_FLAGCNT  10502144   // 1 i32 (zeroed with esum/usage region)
#define WS_P1       10506240   // 4*32768 f32  = 524288
#define WS_P2       11030528   // 4*32768 f32  = 524288
#define WS_PIDX     11554816   // 4*32768 i32  = 524288
#define WS_IDX      12079104   // 32768 i32    = 131072
#define WS_RIDX     12210176   // 4096 i32     = 16384
#define WS_FLAGLIST 12226560   // 32768 i32    = 131072
#define WS_NVAL     12357632   // 1 f32

#define MARGIN 1e-4f

typedef __attribute__((ext_vector_type(8))) short short8;
typedef __attribute__((ext_vector_type(4))) float float4v;

__device__ __forceinline__ float wave_sum(float v) {
#pragma unroll
  for (int off = 32; off > 0; off >>= 1) v += __shfl_xor(v, off, 64);
  return v;
}

// round-to-nearest-even f32 -> bf16 bits
__device__ __forceinline__ unsigned short f2bf(float f) {
  unsigned u = __float_as_uint(f);
  unsigned r = (u + 0x7fffu + ((u >> 16) & 1u)) >> 16;
  return (unsigned short)r;
}
__device__ __forceinline__ float bf2f(unsigned short h) {
  return __uint_as_float(((unsigned)h) << 16);
}

// ---------------- Threefry-2x32 (20 rounds), bit-exact vs JAX ----------------
__device__ __forceinline__ unsigned rotl32(unsigned x, int d) {
  return (x << d) | (x >> (32 - d));
}
__device__ __forceinline__ void tf2x32(unsigned k0, unsigned k1,
                                       unsigned x0, unsigned x1,
                                       unsigned& o0, unsigned& o1) {
  unsigned ks2 = k0 ^ k1 ^ 0x1BD11BDAu;
  unsigned v0 = x0 + k0, v1 = x1 + k1;
  v0 += v1; v1 = rotl32(v1, 13) ^ v0;
  v0 += v1; v1 = rotl32(v1, 15) ^ v0;
  v0 += v1; v1 = rotl32(v1, 26) ^ v0;
  v0 += v1; v1 = rotl32(v1, 6) ^ v0;
  v0 += k1; v1 += ks2 + 1u;
  v0 += v1; v1 = rotl32(v1, 17) ^ v0;
  v0 += v1; v1 = rotl32(v1, 29) ^ v0;
  v0 += v1; v1 = rotl32(v1, 16) ^ v0;
  v0 += v1; v1 = rotl32(v1, 24) ^ v0;
  v0 += ks2; v1 += k0 + 2u;
  v0 += v1; v1 = rotl32(v1, 13) ^ v0;
  v0 += v1; v1 = rotl32(v1, 15) ^ v0;
  v0 += v1; v1 = rotl32(v1, 26) ^ v0;
  v0 += v1; v1 = rotl32(v1, 6) ^ v0;
  v0 += k0; v1 += k1 + 3u;
  v0 += v1; v1 = rotl32(v1, 17) ^ v0;
  v0 += v1; v1 = rotl32(v1, 29) ^ v0;
  v0 += v1; v1 = rotl32(v1, 16) ^ v0;
  v0 += v1; v1 = rotl32(v1, 24) ^ v0;
  v0 += k1; v1 += ks2 + 4u;
  v0 += v1; v1 = rotl32(v1, 13) ^ v0;
  v0 += v1; v1 = rotl32(v1, 15) ^ v0;
  v0 += v1; v1 = rotl32(v1, 26) ^ v0;
  v0 += v1; v1 = rotl32(v1, 6) ^ v0;
  v0 += ks2; v1 += k0 + 5u;
  o0 = v0; o1 = v1;
}

__global__ void k_ridx(int* __restrict__ ridx) {
  int j = blockIdx.x * 256 + threadIdx.x;  // 0..2047
  unsigned a0, b0, a1, b1;
  tf2x32(0u, 1u, 0u, 2u, a0, b0);
  tf2x32(0u, 1u, 1u, 3u, a1, b1);
  unsigned o0, o1;
  tf2x32(b0, b1, (unsigned)j, (unsigned)(j + 2048), o0, o1);
  ridx[j] = (int)(o0 & 32767u);
  ridx[j + 2048] = (int)(o1 & 32767u);
}

// ---------------- emb -> bf16 hi/lo ----------------
__global__ __launch_bounds__(256) void k_prep_emb(const float* __restrict__ emb,
                                                  unsigned short* __restrict__ ehi,
                                                  unsigned short* __restrict__ elo) {
  int i = blockIdx.x * 256 + threadIdx.x;  // < 262144
  float x = emb[i];
  unsigned short h = f2bf(x);
  ehi[i] = h;
  elo[i] = f2bf(x - bf2f(h));
}

// ---------------- normalize rows of z_e -> fn ----------------
__global__ __launch_bounds__(256) void k_norm(const float* __restrict__ z_e,
                                              float* __restrict__ fn) {
  int t = threadIdx.x;
  int n = blockIdx.x * 4 + (t >> 6);
  int lane = t & 63;
  float x = z_e[n * 64 + lane];
  float ss = wave_sum(x * x);
  fn[n * 64 + lane] = x / fmaxf(sqrtf(ss), 1e-8f);
}

// ---------------- MFMA dots + per-split top-2 argmax ----------------
// grid (128, 4). Each wave: 64 queries (4 subtiles of 16), sweeps 1024 codes.
__global__ __launch_bounds__(256, 2) void k_dots_mfma(const float* __restrict__ fn,
                                                      const unsigned short* __restrict__ ehi,
                                                      const unsigned short* __restrict__ elo,
                                                      float* __restrict__ p1,
                                                      float* __restrict__ p2,
                                                      int* __restrict__ pidx) {
  int t = threadIdx.x;
  int wave = t >> 6, lane = t & 63;
  int qwave = blockIdx.x * 256 + wave * 64;
  int split = blockIdx.y;  // 0..3
  int g = lane >> 4;       // k-chunk group
  int n = lane & 15;

  // A fragments: subtile s, kstep ks. lane -> A[m=n][k=ks*32+g*8+j]
  short8 ahi[4][2], alo[4][2];
#pragma unroll
  for (int s = 0; s < 4; s++) {
#pragma unroll
    for (int ks = 0; ks < 2; ks++) {
      const float* src = fn + (qwave + s * 16 + n) * 64 + ks * 32 + g * 8;
      short8 h, l;
#pragma unroll
      for (int j = 0; j < 8; j++) {
        float f = src[j];
        unsigned short hu = f2bf(f);
        h[j] = (short)hu;
        l[j] = (short)f2bf(f - bf2f(hu));
      }
      ahi[s][ks] = h;
      alo[s][ks] = l;
    }
  }

  float run1[4][4], run2[4][4];
  int idx1[4][4];
#pragma unroll
  for (int s = 0; s < 4; s++)
#pragma unroll
    for (int r = 0; r < 4; r++) { run1[s][r] = -1e30f; run2[s][r] = -1e30f; idx1[s][r] = 0; }

  int kbn = split * 1024 + n;  // this lane's code column base
  const unsigned short* bhbase = ehi + kbn * 64 + g * 8;
  const unsigned short* blbase = elo + kbn * 64 + g * 8;

  for (int kt = 0; kt < 64; kt++) {
    int off = kt * 1024;  // 16 codes * 64 dims
    short8 bh0 = *(const short8*)(bhbase + off);
    short8 bh1 = *(const short8*)(bhbase + off + 32);
    short8 bl0 = *(const short8*)(blbase + off);
    short8 bl1 = *(const short8*)(blbase + off + 32);

    float4v acc[4];
#pragma unroll
    for (int s = 0; s < 4; s++) acc[s] = (float4v){0.f, 0.f, 0.f, 0.f};
    // smallest products first; 4 independent chains interleaved
#pragma unroll
    for (int s = 0; s < 4; s++) acc[s] = __builtin_amdgcn_mfma_f32_16x16x32_bf16(alo[s][0], bh0, acc[s], 0, 0, 0);
#pragma unroll
    for (int s = 0; s < 4; s++) acc[s] = __builtin_amdgcn_mfma_f32_16x16x32_bf16(alo[s][1], bh1, acc[s], 0, 0, 0);
#pragma unroll
    for (int s = 0; s < 4; s++) acc[s] = __builtin_amdgcn_mfma_f32_16x16x32_bf16(ahi[s][0], bl0, acc[s], 0, 0, 0);
#pragma unroll
    for (int s = 0; s < 4; s++) acc[s] = __builtin_amdgcn_mfma_f32_16x16x32_bf16(ahi[s][1], bl1, acc[s], 0, 0, 0);
#pragma unroll
    for (int s = 0; s < 4; s++) acc[s] = __builtin_amdgcn_mfma_f32_16x16x32_bf16(ahi[s][0], bh0, acc[s], 0, 0, 0);
#pragma unroll
    for (int s = 0; s < 4; s++) acc[s] = __builtin_amdgcn_mfma_f32_16x16x32_bf16(ahi[s][1], bh1, acc[s], 0, 0, 0);

    int c = kbn + kt * 16;  // code index for this lane's column
#pragma unroll
    for (int s = 0; s < 4; s++)
#pragma unroll
      for (int r = 0; r < 4; r++) {
        float v = acc[s][r];
        bool gt = v > run1[s][r];
        run2[s][r] = gt ? run1[s][r] : fmaxf(run2[s][r], v);
        run1[s][r] = gt ? v : run1[s][r];
        idx1[s][r] = gt ? c : idx1[s][r];
      }
  }

  // butterfly top-2 reduce across the 16 lanes sharing each query group
#pragma unroll
  for (int off = 1; off <= 8; off <<= 1) {
#pragma unroll
    for (int s = 0; s < 4; s++)
#pragma unroll
      for (int r = 0; r < 4; r++) {
        float ov1 = __shfl_xor(run1[s][r], off, 64);
        float ov2 = __shfl_xor(run2[s][r], off, 64);
        int oi1 = __shfl_xor(idx1[s][r], off, 64);
        if (ov1 > run1[s][r]) {
          run2[s][r] = fmaxf(run1[s][r], ov2);
          run1[s][r] = ov1;
          idx1[s][r] = oi1;
        } else if (ov1 == run1[s][r]) {
          run2[s][r] = run1[s][r];  // genuine tie between distinct codes -> flag
          idx1[s][r] = min(idx1[s][r], oi1);
        } else {
          run2[s][r] = fmaxf(run2[s][r], ov1);
        }
      }
  }

  if (n == 0) {
#pragma unroll
    for (int s = 0; s < 4; s++)
#pragma unroll
      for (int r = 0; r < 4; r++) {
        int q = qwave + s * 16 + g * 4 + r;
        p1[split * N_TOK + q] = run1[s][r];
        p2[split * N_TOK + q] = run2[s][r];
        pidx[split * N_TOK + q] = idx1[s][r];
      }
  }
}

// ---------------- combine splits + flag near-ties + gather ----------------
__global__ __launch_bounds__(256) void k_gather(const float* __restrict__ p1,
                                                const float* __restrict__ p2,
                                                const int* __restrict__ pidx,
                                                const float* __restrict__ z_e,
                                                const float* __restrict__ emb,
                                                float* __restrict__ out,
                                                int* __restrict__ idxw,
                                                int* __restrict__ flagcnt,
                                                int* __restrict__ flaglist) {
  int t = threadIdx.x;
  int q = blockIdx.x * 4 + (t >> 6);
  int lane = t & 63;
  float best1 = -1e30f, best2 = -1e30f;
  int bi = 0;
#pragma unroll
  for (int s = 0; s < 4; s++) {
    float v1 = p1[s * N_TOK + q];
    float v2 = p2[s * N_TOK + q];
    int i1 = pidx[s * N_TOK + q];
    if (v1 > best1) {
      best2 = fmaxf(best1, v2);
      best1 = v1;
      bi = i1;
    } else if (v1 == best1) {
      best2 = best1;
      bi = min(bi, i1);
    } else {
      best2 = fmaxf(best2, v1);
    }
  }
  float v = emb[bi * 64 + lane];
  float ze = z_e[q * 64 + lane];
  out[OFF_ZQST + q * 64 + lane] = ze + (v - ze);
  out[OFF_ZQ + q * 64 + lane] = v;
  if (lane == 0) {
    idxw[q] = bi;
    out[OFF_IDX + q] = (float)bi;
    if (best1 - best2 < MARGIN) {
      int pos = atomicAdd(flagcnt, 1);
      flaglist[pos] = q;
    }
  }
}

// ---------------- exact fp64 rescore of flagged queries ----------------
__global__ __launch_bounds__(256) void k_fix(const int* __restrict__ flagcnt,
                                             const int* __restrict__ flaglist,
                                             const float* __restrict__ fn,
                                             const float* __restrict__ emb,
                                             const float* __restrict__ z_e,
                                             float* __restrict__ out,
                                             int* __restrict__ idxw) {
  __shared__ float sfn[64];
  __shared__ double sv[256];
  __shared__ int si[256];
  int t = threadIdx.x;
  int cnt = flagcnt[0];
  for (int i = blockIdx.x; i < cnt; i += gridDim.x) {
    int q = flaglist[i];
    if (t < 64) sfn[t] = fn[q * 64 + t];
    __syncthreads();
    double best = -1e300;
    int bi = 0;
    for (int c = t; c < KCB; c += 256) {
      double d = 0.0;
      for (int k = 0; k < 64; k++) d += (double)emb[c * 64 + k] * (double)sfn[k];
      if (d > best) { best = d; bi = c; }
    }
    sv[t] = best;
    si[t] = bi;
    __syncthreads();
    for (int s2 = 128; s2 > 0; s2 >>= 1) {
      if (t < s2) {
        if (sv[t + s2] > sv[t] || (sv[t + s2] == sv[t] && si[t + s2] < si[t])) {
          sv[t] = sv[t + s2];
          si[t] = si[t + s2];
        }
      }
      __syncthreads();
    }
    int win = si[0];
    if (t < 64) {
      float v = emb[win * 64 + t];
      float ze = z_e[q * 64 + t];
      out[OFF_ZQST + q * 64 + t] = ze + (v - ze);
      out[OFF_ZQ + q * 64 + t] = v;
    }
    if (t == 0) {
      idxw[q] = win;
      out[OFF_IDX + q] = (float)win;
    }
    __syncthreads();
  }
}

// ---------------- scatter: usage bincount + embed_sum ----------------
__global__ __launch_bounds__(256) void k_scatter(const int* __restrict__ idxw,
                                                 const float* __restrict__ fn,
                                                 float* __restrict__ esum,
                                                 float* __restrict__ usage) {
  int t = threadIdx.x;
  int n = blockIdx.x * 4 + (t >> 6);
  int lane = t & 63;
  int bi = idxw[n];
  atomicAdd(&esum[bi * 64 + lane], fn[n * 64 + lane]);
  if (lane == 0) atomicAdd(&usage[bi], 1.0f);
}

// ---------------- stats + n = sum(new_cs) ----------------
__device__ __forceinline__ float block_reduce256(float v, float* r, int t) {
  r[t] = v;
  __syncthreads();
  for (int s = 128; s > 0; s >>= 1) {
    if (t < s) r[t] += r[t + s];
    __syncthreads();
  }
  float res = r[0];
  __syncthreads();
  return res;
}

__global__ __launch_bounds__(256) void k_stats(const float* __restrict__ usage,
                                               const float* __restrict__ ema_cs,
                                               float* __restrict__ out,
                                               float* __restrict__ nval) {
  __shared__ float r[256];
  int t = threadIdx.x;
  float su = 0.f, sd = 0.f, scs = 0.f;
  for (int i = t; i < KCB; i += 256) {
    float u = usage[i];
    su += u;
    sd += (u == 0.f) ? 1.f : 0.f;
    scs += 0.99f * ema_cs[i] + 0.01f * u;
  }
  float tot_u = block_reduce256(su, r, t);
  float tot_d = block_reduce256(sd, r, t);
  float tot_cs = block_reduce256(scs, r, t);
  float denom = fmaxf(tot_u, 1.0f);
  float ent = 0.f;
  for (int i = t; i < KCB; i += 256) {
    float p = usage[i] / denom;
    if (p > 0.f) ent += p * logf(p);
  }
  float tot_e = block_reduce256(ent, r, t);
  if (t == 0) {
    out[OFF_STATS + 0] = expf(-tot_e);
    out[OFF_STATS + 1] = tot_d * (1.0f / 4096.0f);
    nval[0] = tot_cs;
  }
}

// ---------------- new_cs, new_ema_emb, new_embedding ----------------
__global__ __launch_bounds__(256) void k_final(const float* __restrict__ usage,
                                               const float* __restrict__ ema_cs,
                                               const float* __restrict__ ema_emb,
                                               const float* __restrict__ esum,
                                               const float* __restrict__ fn,
                                               const int* __restrict__ ridx,
                                               const float* __restrict__ nval,
                                               float* __restrict__ out) {
  int t = threadIdx.x;
  int k = blockIdx.x * 4 + (t >> 6);
  int lane = t & 63;
  float u = usage[k];
  float ncs = 0.99f * ema_cs[k] + 0.01f * u;
  if (lane == 0) out[OFF_NEWCS + k] = ncs;
  float nee = 0.99f * ema_emb[k * 64 + lane] + 0.01f * esum[k * 64 + lane];
  out[OFF_NEWEMA + k * 64 + lane] = nee;

  float n = nval[0];
  float smoothed = (ncs + 1e-5f) / (n + 4096.0f * 1e-5f);
  float ne = nee / fmaxf(smoothed, 1e-5f);
  float ss = wave_sum(ne * ne);
  ne = ne / fmaxf(sqrtf(ss), 1e-8f);

  float res;
  if (u <= 0.f) {
    int rsrc = ridx[k];
    float v = fn[rsrc * 64 + lane];
    float s2 = wave_sum(v * v);
    res = v / fmaxf(sqrtf(s2), 1e-8f);
  } else {
    res = ne;
  }
  out[OFF_NEWEMB + k * 64 + lane] = res;
}

extern "C" void kernel_launch(void* const* d_in, const int* in_sizes, int n_in,
                              void* d_out, int out_size, void* d_ws, size_t ws_size,
                              hipStream_t stream) {
  const float* z_e = (const float*)d_in[0];
  const float* emb = (const float*)d_in[1];
  const float* ema_cs = (const float*)d_in[2];
  const float* ema_emb = (const float*)d_in[3];
  float* out = (float*)d_out;
  char* ws = (char*)d_ws;

  float* fn = (float*)(ws + WS_FN);
  unsigned short* ehi = (unsigned short*)(ws + WS_EHI);
  unsigned short* elo = (unsigned short*)(ws + WS_ELO);
  float* esum = (float*)(ws + WS_ESUM);
  float* usage = (float*)(ws + WS_USAGE);
  int* flagcnt = (int*)(ws + WS_FLAGCNT);
  float* p1 = (float*)(ws + WS_P1);
  float* p2 = (float*)(ws + WS_P2);
  int* pidx = (int*)(ws + WS_PIDX);
  int* idxw = (int*)(ws + WS_IDX);
  int* ridx = (int*)(ws + WS_RIDX);
  int* flaglist = (int*)(ws + WS_FLAGLIST);
  float* nval = (float*)(ws + WS_NVAL);

  // zero esum + usage + flagcnt (contiguous)
  hipMemsetAsync(ws + WS_ESUM, 0, 1048576 + 16384 + 4, stream);

  k_ridx<<<8, 256, 0, stream>>>(ridx);
  k_prep_emb<<<1024, 256, 0, stream>>>(emb, ehi, elo);
  k_norm<<<8192, 256, 0, stream>>>(z_e, fn);
  k_dots_mfma<<<dim3(128, 4), 256, 0, stream>>>(fn, ehi, elo, p1, p2, pidx);
  k_gather<<<8192, 256, 0, stream>>>(p1, p2, pidx, z_e, emb, out, idxw, flagcnt, flaglist);
  k_fix<<<64, 256, 0, stream>>>(flagcnt, flaglist, fn, emb, z_e, out, idxw);
  k_scatter<<<8192, 256, 0, stream>>>(idxw, fn, esum, usage);
  k_stats<<<1, 256, 0, stream>>>(usage, ema_cs, out, nval);
  k_final<<<1024, 256, 0, stream>>>(usage, ema_cs, ema_emb, esum, fn, ridx, nval, out);
}